// Round 16
// baseline (571.342 us; speedup 1.0000x reference)
//
#include <hip/hip_runtime.h>
#include <hip/hip_bf16.h>

#define BATCH  4096
#define NCC    64
#define HDIM   256
#define G3     768
#define NROW   (BATCH*NCC)   // 262144
#define NK     20
#define LOG2PI 1.8378770664093453f

typedef __attribute__((ext_vector_type(8))) short bf16x8;
typedef __attribute__((ext_vector_type(4))) float f32x4;

__device__ __forceinline__ float sigm(float x) { return 1.0f/(1.0f + __expf(-x)); }
__device__ __forceinline__ float tanh_fast(float x) { return 1.0f - 2.0f/(__expf(2.0f*x) + 1.0f); }
__device__ __forceinline__ unsigned short f2bf(float x) {
  __hip_bfloat16 h = __float2bfloat16(x);
  return __builtin_bit_cast(unsigned short, h);
}
__device__ __forceinline__ int swz(int r) { return (r & 7) ^ ((r & 8) >> 2); }

// ---- one elementwise pass: build cbmB, CW, WhhB, W1aB, W2B, W3pB, w0 ----
__global__ __launch_bounds__(256) void k_cvtall(
    const float* __restrict__ c, const float* __restrict__ bv,
    const float* __restrict__ mv, const float* __restrict__ W_ih,
    const float* __restrict__ W_hh, const float* __restrict__ W1,
    const float* __restrict__ W2, const float* __restrict__ W3,
    unsigned short* __restrict__ cbmB, unsigned short* __restrict__ CW,
    unsigned short* __restrict__ WhhB, unsigned short* __restrict__ W1aB,
    unsigned short* __restrict__ W2B, unsigned short* __restrict__ W3pB,
    float* __restrict__ w0) {
  int idx = blockIdx.x*256 + threadIdx.x;
  if (idx < 1048576) {            // cbmB [4096][256], K-padded
    int row = idx >> 8, k = idx & 255;
    float v = 0.f;
    if (k < 80)       v = c [row*80 + k];
    else if (k < 144) v = bv[row*64 + (k-80)];
    else if (k < 208) v = mv[row*64 + (k-144)];
    cbmB[idx] = f2bf(v);
    return;
  }
  idx -= 1048576;
  if (idx < 262144) {             // CW [1024][256]: W_ih cols 1.. | W1 cols 256..
    int n = idx >> 8, k = idx & 255;
    float v = 0.f;
    if (n < 768) { if (k < 208) v = W_ih[n*209 + 1 + k]; }
    else         { if (k < 208) v = W1[(n-768)*464 + 256 + k]; }
    CW[idx] = f2bf(v);
    return;
  }
  idx -= 262144;
  if (idx < 196608) { WhhB[idx] = f2bf(W_hh[idx]); return; }
  idx -= 196608;
  if (idx < 65536) { int n = idx>>8, k = idx&255; W1aB[idx] = f2bf(W1[n*464+k]); return; }
  idx -= 65536;
  if (idx < 65536) { W2B[idx] = f2bf(W2[idx]); return; }
  idx -= 65536;
  if (idx < 16384) {
    int n = idx >> 8;
    float v = 0.f;
    if (n < 60) v = W3[idx];
    W3pB[idx] = f2bf(v);
    return;
  }
  idx -= 16384;
  if (idx < 768) w0[idx] = W_ih[idx*209];
}

// ---- pre-GEMM: [4096 x 1024 x 256(pad)] -> gi (+biases) / P1 (+b1) ----
__global__ __launch_bounds__(512) void k_pre(
    const unsigned short* __restrict__ A, const unsigned short* __restrict__ Bw,
    const float* __restrict__ b_ih, const float* __restrict__ b_hh,
    const float* __restrict__ b1,
    float* __restrict__ gi, float* __restrict__ P1) {
  __shared__ __align__(16) unsigned short As[128*64];
  __shared__ __align__(16) unsigned short Bs[128*64];
  int tid = threadIdx.x;
  int rb = blockIdx.x >> 3, cb = blockIdx.x & 7;
  long row0 = (long)rb * 128;
  int n0 = cb * 128;
  int wv = tid >> 6, lane = tid & 63;
  int lq = lane >> 4, l16 = lane & 15;
  int wrg = wv & 3, wcg = wv >> 2;
  f32x4 acc[2][4];
#pragma unroll
  for (int i = 0; i < 2; ++i)
#pragma unroll
    for (int j = 0; j < 4; ++j) acc[i][j] = (f32x4){0.f,0.f,0.f,0.f};
  for (int kb = 0; kb < 256; kb += 64) {
#pragma unroll
    for (int i = 0; i < 2; ++i) {
      int s = i*512 + tid;
      int r = s >> 3, cg = (s & 7) ^ (r & 7);
      *(uint4*)&As[s*8] = *(const uint4*)&A[(row0 + r)*256 + kb + cg*8];
      *(uint4*)&Bs[s*8] = *(const uint4*)&Bw[(long)(n0 + r)*256 + kb + cg*8];
    }
    __syncthreads();
#pragma unroll
    for (int kc = 0; kc < 2; ++kc) {
      int csel = kc*4 + lq;
      bf16x8 af[2];
#pragma unroll
      for (int rt = 0; rt < 2; ++rt) {
        int r = wrg*32 + rt*16 + l16;
        af[rt] = *(const bf16x8*)&As[r*64 + ((csel ^ (r & 7)))*8];
      }
#pragma unroll
      for (int ct = 0; ct < 4; ++ct) {
        int n = wcg*64 + ct*16 + l16;
        bf16x8 bfr = *(const bf16x8*)&Bs[n*64 + ((csel ^ (n & 7)))*8];
        acc[0][ct] = __builtin_amdgcn_mfma_f32_16x16x32_bf16(af[0], bfr, acc[0][ct], 0, 0, 0);
        acc[1][ct] = __builtin_amdgcn_mfma_f32_16x16x32_bf16(af[1], bfr, acc[1][ct], 0, 0, 0);
      }
    }
    __syncthreads();
  }
#pragma unroll
  for (int rt = 0; rt < 2; ++rt)
#pragma unroll
    for (int q = 0; q < 4; ++q) {
      long row = row0 + wrg*32 + rt*16 + lq*4 + q;
#pragma unroll
      for (int ct = 0; ct < 4; ++ct) {
        int n = n0 + wcg*64 + ct*16 + l16;
        float v = acc[rt][ct][q];
        if (n < 512)      gi[row*G3 + n] = v + b_ih[n] + b_hh[n];
        else if (n < 768) gi[row*G3 + n] = v + b_ih[n];
        else              P1[row*256 + (n-768)] = v + b1[n-768];
      }
    }
}

// ---- persistent GRU (R14/R15 best, ~263 us): 256 blocks x 16 rows, 512 thr.
// Whh streams from L2 each step (compiler remats the loads; all residency
// attempts R7-R13 failed). ~70% of the per-XCD L2-BW bound. ----
__global__ __attribute__((amdgpu_flat_work_group_size(512, 512)))
__attribute__((amdgpu_waves_per_eu(2, 2)))
void k_gru(
    const float* __restrict__ z, const float* __restrict__ gi,
    const unsigned short* __restrict__ WhhB, const float* __restrict__ b_hh,
    const float* __restrict__ w0, unsigned short* __restrict__ hs) {
  __shared__ __align__(16) unsigned short hbf[2*16*256];  // two 8 KB buffers
  __shared__ __align__(16) float gis[768*20];             // gi^T, stride 20 fp32
  __shared__ __align__(16) float zs[64*16];               // z^T [t][row]
  __shared__ float wls[768 + 256];                        // w0 | b_hh n-gate
  int tid = threadIdx.x;
  int wv = tid >> 6, lane = tid & 63;
  int lq = lane >> 4, l16 = lane & 15;
  int row0 = blockIdx.x * 16;
  bf16x8 wf[6][8];
#pragma unroll
  for (int g = 0; g < 3; ++g)
#pragma unroll
    for (int tt = 0; tt < 2; ++tt)
#pragma unroll
      for (int ks = 0; ks < 8; ++ks)
        wf[g*2+tt][ks] = *(const bf16x8*)&WhhB[(long)(g*256 + wv*32 + tt*16 + l16)*256 + ks*32 + lq*8];
  for (int i = tid; i < 768; i += 512) wls[i] = w0[i];
  for (int i = tid; i < 256; i += 512) wls[768 + i] = b_hh[512 + i];
  for (int i = tid; i < 1024; i += 512) {
    int t = i >> 4, r = i & 15;
    zs[i] = z[(row0+r)*64 + t];
  }
#pragma unroll
  for (int i = 0; i < 24; ++i) {
    int s = i*512 + tid;
    int r = s / 768, cc = s - r*768;
    gis[cc*20 + r] = gi[(long)(row0+r)*768 + cc];
  }
  for (int i = tid; i < 2048; i += 512) ((unsigned int*)hbf)[i] = 0u;
  float hp[2][4] = {{0.f,0.f,0.f,0.f},{0.f,0.f,0.f,0.f}};
  const int s7 = l16 & 7;
  const int arow = l16*256;
  const int r4 = lq*4;
  const int hc0 = wv*32 + l16;
  const int cr = tid >> 5, ccc = tid & 31;
  const int csrc = cr*256 + ((ccc ^ (cr & 7)))*8;
  unsigned short* cbase = hs + (long)(row0+cr)*64*256 + ccc*8;
  __syncthreads();
#pragma unroll 1
  for (int t = 0; t < 64; ++t) {
    const int co = (t & 1) << 12;
    const int no = co ^ 4096;
    float zp[4];
    {
      float4 zv4 = *(const float4*)&zs[(t ? (t-1) : 0)*16 + r4];
#pragma unroll
      for (int q = 0; q < 4; ++q) zp[q] = t ? (&zv4.x)[q] : -1.0f;
    }
    f32x4 a[6];
#pragma unroll
    for (int tt = 0; tt < 2; ++tt) {
      int hc = hc0 + tt*16;
      f32x4 gR = *(const f32x4*)&gis[hc*20 + r4];
      f32x4 gU = *(const f32x4*)&gis[(256+hc)*20 + r4];
      float w0r = wls[hc], w0u = wls[256+hc], bn = wls[768 + hc];
#pragma unroll
      for (int q = 0; q < 4; ++q) {
        a[tt][q]   = gR[q] + zp[q]*w0r;
        a[2+tt][q] = gU[q] + zp[q]*w0u;
        a[4+tt][q] = bn;
      }
    }
#pragma unroll
    for (int ks = 0; ks < 8; ++ks) {
      bf16x8 af = *(const bf16x8*)&hbf[co + arow + (((ks*4+lq) ^ s7))*8];
#pragma unroll
      for (int f = 0; f < 6; ++f)
        a[f] = __builtin_amdgcn_mfma_f32_16x16x32_bf16(af, wf[f][ks], a[f], 0, 0, 0);
    }
    if (t) {
      uint4 cdat = *(const uint4*)&hbf[co + csrc];
      *(uint4*)(cbase + (t-1)*256) = cdat;
    }
#pragma unroll
    for (int tt = 0; tt < 2; ++tt) {
      int hc = hc0 + tt*16;
      int hchunk = hc >> 3, hlow = hc & 7;
      float w0n = wls[512 + hc];
      f32x4 gN = *(const f32x4*)&gis[(512+hc)*20 + r4];
#pragma unroll
      for (int q = 0; q < 4; ++q) {
        int r = r4 + q;
        float rr = sigm(a[tt][q]);
        float uu = sigm(a[2+tt][q]);
        float nn = tanh_fast(gN[q] + zp[q]*w0n + rr*a[4+tt][q]);
        float hn = uu*(hp[tt][q] - nn) + nn;
        hp[tt][q] = hn;
        hbf[no + r*256 + ((hchunk ^ (r & 7)))*8 + hlow] = f2bf(hn);
      }
    }
    __syncthreads();
  }
  uint4 cdat = *(const uint4*)&hbf[0 + csrc];
  *(uint4*)(cbase + 63*256) = cdat;
}

// ---- MLP layer 1, in-place: Out = tanh(A @ W1a^T + P1[row>>6]) ----
__global__ __launch_bounds__(512) void k_l1(
    const unsigned short* __restrict__ A, const unsigned short* __restrict__ Bw,
    const float* __restrict__ P1, unsigned short* __restrict__ Out) {
  __shared__ __align__(16) unsigned short As[128*64];
  __shared__ __align__(16) unsigned short Bs[256*64];
  int tid = threadIdx.x;
  long row0 = (long)blockIdx.x * 128;
  int wv = tid >> 6, lane = tid & 63;
  int lq = lane >> 4, l16 = lane & 15;
  int wrg = wv & 3, wcg = wv >> 2;
  f32x4 acc[2][8];
#pragma unroll
  for (int i = 0; i < 2; ++i)
#pragma unroll
    for (int j = 0; j < 8; ++j) acc[i][j] = (f32x4){0.f,0.f,0.f,0.f};
  for (int kb = 0; kb < 256; kb += 64) {
#pragma unroll
    for (int i = 0; i < 2; ++i) {
      int s = i*512 + tid;
      int r = s >> 3, cg = (s & 7) ^ (r & 7);
      *(uint4*)&As[s*8] = *(const uint4*)&A[(row0 + r)*256 + kb + cg*8];
    }
#pragma unroll
    for (int i = 0; i < 4; ++i) {
      int s = i*512 + tid;
      int r = s >> 3, cg = (s & 7) ^ (r & 7);
      *(uint4*)&Bs[s*8] = *(const uint4*)&Bw[(long)r*256 + kb + cg*8];
    }
    __syncthreads();
#pragma unroll
    for (int kc = 0; kc < 2; ++kc) {
      int csel = kc*4 + lq;
      bf16x8 af[2];
#pragma unroll
      for (int rt = 0; rt < 2; ++rt) {
        int r = wrg*32 + rt*16 + l16;
        af[rt] = *(const bf16x8*)&As[r*64 + ((csel ^ (r & 7)))*8];
      }
#pragma unroll
      for (int ct = 0; ct < 8; ++ct) {
        int n = wcg*128 + ct*16 + l16;
        bf16x8 bfr = *(const bf16x8*)&Bs[n*64 + ((csel ^ (n & 7)))*8];
        acc[0][ct] = __builtin_amdgcn_mfma_f32_16x16x32_bf16(af[0], bfr, acc[0][ct], 0, 0, 0);
        acc[1][ct] = __builtin_amdgcn_mfma_f32_16x16x32_bf16(af[1], bfr, acc[1][ct], 0, 0, 0);
      }
    }
    __syncthreads();
  }
#pragma unroll
  for (int rt = 0; rt < 2; ++rt)
#pragma unroll
    for (int q = 0; q < 4; ++q) {
      long row = row0 + wrg*32 + rt*16 + lq*4 + q;
#pragma unroll
      for (int ct = 0; ct < 8; ++ct) {
        int n = wcg*128 + ct*16 + l16;
        float b = P1[(row >> 6)*256 + n];
        Out[row*256 + n] = f2bf(tanh_fast(acc[rt][ct][q] + b));
      }
    }
}

// ---- fused MLP layer2 + layer3 + likelihood, LDS-dieted to 65 KB ----
// (R15's version used 112 KB -> 1 block/CU -> latency-bound on hs reads.)
// Bs is reused as h2-half buffer [64][256] after the W2 K-loop; W3p streams
// through As in two K=128 chunks; Ps is a small separate region.
// 16+32+17 KB = 65 KB -> 2 blocks/CU.
__global__ __launch_bounds__(512) void k_l23(
    const unsigned short* __restrict__ A, const unsigned short* __restrict__ W2B,
    const float* __restrict__ b2, const unsigned short* __restrict__ W3pB,
    const float* __restrict__ b3, const float* __restrict__ z,
    float* __restrict__ ll) {
  __shared__ __align__(16) unsigned short As[128*64];   // h1 K-slab -> W3p chunk [64][128]
  __shared__ __align__(16) unsigned short Bs[256*64];   // W2 K-slab -> h2 half [64][256]
  __shared__ float Ps[64*68];                           // 17 KB params
  int tid = threadIdx.x;
  long row0 = (long)blockIdx.x * 128;
  int wv = tid >> 6, lane = tid & 63;
  int lq = lane >> 4, l16 = lane & 15;
  int wrg = wv & 3, wcg = wv >> 2;
  // ---------- layer 2 GEMM: acc = h1 @ W2^T (rows 128, cols 256) ----------
  f32x4 acc[2][8];
#pragma unroll
  for (int i = 0; i < 2; ++i)
#pragma unroll
    for (int j = 0; j < 8; ++j) acc[i][j] = (f32x4){0.f,0.f,0.f,0.f};
  for (int kb = 0; kb < 256; kb += 64) {
#pragma unroll
    for (int i = 0; i < 2; ++i) {
      int s = i*512 + tid;
      int r = s >> 3, cg = (s & 7) ^ (r & 7);
      *(uint4*)&As[s*8] = *(const uint4*)&A[(row0 + r)*256 + kb + cg*8];
    }
#pragma unroll
    for (int i = 0; i < 4; ++i) {
      int s = i*512 + tid;
      int r = s >> 3, cg = (s & 7) ^ (r & 7);
      *(uint4*)&Bs[s*8] = *(const uint4*)&W2B[(long)r*256 + kb + cg*8];
    }
    __syncthreads();
#pragma unroll
    for (int kc = 0; kc < 2; ++kc) {
      int csel = kc*4 + lq;
      bf16x8 af[2];
#pragma unroll
      for (int rt = 0; rt < 2; ++rt) {
        int r = wrg*32 + rt*16 + l16;
        af[rt] = *(const bf16x8*)&As[r*64 + ((csel ^ (r & 7)))*8];
      }
#pragma unroll
      for (int ct = 0; ct < 8; ++ct) {
        int n = wcg*128 + ct*16 + l16;
        bf16x8 bfr = *(const bf16x8*)&Bs[n*64 + ((csel ^ (n & 7)))*8];
        acc[0][ct] = __builtin_amdgcn_mfma_f32_16x16x32_bf16(af[0], bfr, acc[0][ct], 0, 0, 0);
        acc[1][ct] = __builtin_amdgcn_mfma_f32_16x16x32_bf16(af[1], bfr, acc[1][ct], 0, 0, 0);
      }
    }
    __syncthreads();
  }
  // ---------- two 64-row halves: h2 -> Bs overlay, L3 GEMM, likelihood ----
  for (int half = 0; half < 2; ++half) {
    // waves owning this half's rows write h2 = tanh(acc + b2) into Bs[64][256]
    if ((wrg >> 1) == half) {
#pragma unroll
      for (int rt = 0; rt < 2; ++rt)
#pragma unroll
        for (int q = 0; q < 4; ++q) {
          int lr = (wrg & 1)*32 + rt*16 + lq*4 + q;   // local row in half
#pragma unroll
          for (int ct = 0; ct < 8; ++ct) {
            int n = wcg*128 + ct*16 + l16;
            Bs[lr*256 + (((n >> 3) ^ swz(lr))*8 + (n & 7))] =
                f2bf(tanh_fast(acc[rt][ct][q] + b2[n]));
          }
        }
    }
    __syncthreads();
    // L3: params[64][64] = h2h @ W3p^T, K=256 in 2 chunks of 128
    int tile = wv*2;                     // each wave: 2 of 16 (16x16) tiles
    f32x4 pacc[2];
    pacc[0] = (f32x4){0.f,0.f,0.f,0.f};
    pacc[1] = (f32x4){0.f,0.f,0.f,0.f};
    for (int c2 = 0; c2 < 2; ++c2) {
      // stage W3p chunk: As[64][128] swizzled (1024 uint4, 2/thread)
#pragma unroll
      for (int i = 0; i < 2; ++i) {
        int s = i*512 + tid;
        int r = s >> 4, kc = s & 15;
        *(uint4*)&As[r*128 + ((kc ^ (r & 7))*8)] =
            *(const uint4*)&W3pB[r*256 + c2*128 + kc*8];
      }
      __syncthreads();
#pragma unroll
      for (int km = 0; km < 4; ++km) {
#pragma unroll
        for (int j = 0; j < 2; ++j) {
          int rt3 = (tile + j) >> 2, ct3 = (tile + j) & 3;
          int ar = rt3*16 + l16;
          bf16x8 af = *(const bf16x8*)&Bs[ar*256 + (((c2*16 + km*4 + lq) ^ swz(ar)))*8];
          int bn = ct3*16 + l16;
          bf16x8 bfr = *(const bf16x8*)&As[bn*128 + (((km*4 + lq) ^ (bn & 7)))*8];
          pacc[j] = __builtin_amdgcn_mfma_f32_16x16x32_bf16(af, bfr, pacc[j], 0, 0, 0);
        }
      }
      __syncthreads();
    }
    // params + b3 -> Ps
#pragma unroll
    for (int j = 0; j < 2; ++j) {
      int rt3 = (tile + j) >> 2, ct3 = (tile + j) & 3;
      int n = ct3*16 + l16;
      float b = (n < 60) ? b3[n] : 0.0f;
#pragma unroll
      for (int q = 0; q < 4; ++q)
        Ps[(rt3*16 + lq*4 + q)*68 + n] = pacc[j][q] + b;
    }
    __syncthreads();
    // likelihood for these 64 rows
    if (wv < 4 && lane < 16) {
      int lr = wv*16 + lane;
      long grow = row0 + half*64 + lr;
      float zv = z[grow];
      const float* p = &Ps[lr*68];
      float mx1 = -1e30f;
#pragma unroll
      for (int i = 0; i < NK; ++i) mx1 = fmaxf(mx1, p[i]);
      float s1 = 0.0f;
#pragma unroll
      for (int i = 0; i < NK; ++i) s1 += __expf(p[i] - mx1);
      float lse1 = mx1 + __logf(s1);
      float a[NK];
      float mx2 = -1e30f;
#pragma unroll
      for (int i = 0; i < NK; ++i) {
        float lg = p[i], me = p[20+i], ls = p[40+i];
        float e = __expf(-ls);
        float d = (zv - me) * e;
        float ai = -0.5f*d*d - ls - 0.5f*LOG2PI + lg;
        a[i] = ai;
        mx2 = fmaxf(mx2, ai);
      }
      float s2 = 0.0f;
#pragma unroll
      for (int i = 0; i < NK; ++i) s2 += __expf(a[i] - mx2);
      float lse2 = mx2 + __logf(s2);
      ll[grow] = lse2 - lse1;
    }
    __syncthreads();   // h2h/As free for next half
  }
}

// out[b] = sum_{t < S_b} ll[b,t]
__global__ __launch_bounds__(256) void k_final(const float* __restrict__ bv,
    const float* __restrict__ mv, const float* __restrict__ ll,
    float* __restrict__ out) {
  int tid = threadIdx.x;
  int wave = tid >> 6, lane = tid & 63;
  int b = blockIdx.x*4 + wave;
  float q = mv[b*64 + lane] * (1.0f - bv[b*64 + lane]);
  unsigned long long bal = __ballot(q > 0.5f);
  int S = __popcll(bal);
  float val = (lane < S) ? ll[(long)b*64 + lane] : 0.0f;
#pragma unroll
  for (int off = 32; off > 0; off >>= 1) val += __shfl_down(val, off);
  if (lane == 0) out[b] = val;
}

extern "C" void kernel_launch(void* const* d_in, const int* in_sizes, int n_in,
                              void* d_out, int out_size, void* d_ws, size_t ws_size,
                              hipStream_t stream) {
  const float* z    = (const float*)d_in[0];
  const float* c    = (const float*)d_in[1];
  const float* bv   = (const float*)d_in[2];
  const float* mv   = (const float*)d_in[3];
  const float* W_ih = (const float*)d_in[4];
  const float* W_hh = (const float*)d_in[5];
  const float* b_ih = (const float*)d_in[6];
  const float* b_hh = (const float*)d_in[7];
  const float* W1   = (const float*)d_in[8];
  const float* b1   = (const float*)d_in[9];
  const float* W2   = (const float*)d_in[10];
  const float* b2   = (const float*)d_in[11];
  const float* W3   = (const float*)d_in[12];
  const float* b3   = (const float*)d_in[13];
  float* out = (float*)d_out;

  char* p = (char*)d_ws;
  auto alloc = [&](size_t bytes) {
    char* q = p;
    p += (bytes + 255) & ~(size_t)255;
    return q;
  };
  unsigned short* cbmB = (unsigned short*)alloc((size_t)BATCH*256*2);
  unsigned short* CW   = (unsigned short*)alloc((size_t)1024*256*2);
  unsigned short* WhhB = (unsigned short*)alloc((size_t)G3*256*2);
  unsigned short* W1aB = (unsigned short*)alloc((size_t)256*256*2);
  unsigned short* W2B  = (unsigned short*)alloc((size_t)256*256*2);
  unsigned short* W3pB = (unsigned short*)alloc((size_t)64*256*2);
  float* w0 = (float*)alloc((size_t)G3*4);
  float* gi = (float*)alloc((size_t)BATCH*G3*4);
  float* P1 = (float*)alloc((size_t)BATCH*256*4);
  float* ll = (float*)alloc((size_t)NROW*4);
  unsigned short* hs = (unsigned short*)alloc((size_t)NROW*HDIM*2);

  k_cvtall<<<6468, 256, 0, stream>>>(c, bv, mv, W_ih, W_hh, W1, W2, W3,
                                     cbmB, CW, WhhB, W1aB, W2B, W3pB, w0);
  k_pre<<<256, 512, 0, stream>>>(cbmB, CW, b_ih, b_hh, b1, gi, P1);
  k_gru<<<256, 512, 0, stream>>>(z, gi, WhhB, b_hh, w0, hs);
  k_l1<<<NROW/128, 512, 0, stream>>>(hs, W1aB, P1, hs);
  k_l23<<<NROW/128, 512, 0, stream>>>(hs, W2B, b2, W3pB, b3, z, ll);
  k_final<<<BATCH/4, 256, 0, stream>>>(bv, mv, ll, out);
}

// Round 17
// 520.925 us; speedup vs baseline: 1.0968x; 1.0968x over previous
//
#include <hip/hip_runtime.h>
#include <hip/hip_bf16.h>

#define BATCH  4096
#define NCC    64
#define HDIM   256
#define G3     768
#define NROW   (BATCH*NCC)   // 262144
#define NK     20
#define LOG2PI 1.8378770664093453f

typedef __attribute__((ext_vector_type(8))) short bf16x8;
typedef __attribute__((ext_vector_type(4))) float f32x4;

__device__ __forceinline__ float sigm(float x) { return 1.0f/(1.0f + __expf(-x)); }
__device__ __forceinline__ float tanh_fast(float x) { return 1.0f - 2.0f/(__expf(2.0f*x) + 1.0f); }
__device__ __forceinline__ unsigned short f2bf(float x) {
  __hip_bfloat16 h = __float2bfloat16(x);
  return __builtin_bit_cast(unsigned short, h);
}
__device__ __forceinline__ int swz(int r) { return (r & 7) ^ ((r & 8) >> 2); }

// ---- one elementwise pass: build cbmB, CW, WhhB, W1aB, W2B, W3pB, w0 ----
__global__ __launch_bounds__(256) void k_cvtall(
    const float* __restrict__ c, const float* __restrict__ bv,
    const float* __restrict__ mv, const float* __restrict__ W_ih,
    const float* __restrict__ W_hh, const float* __restrict__ W1,
    const float* __restrict__ W2, const float* __restrict__ W3,
    unsigned short* __restrict__ cbmB, unsigned short* __restrict__ CW,
    unsigned short* __restrict__ WhhB, unsigned short* __restrict__ W1aB,
    unsigned short* __restrict__ W2B, unsigned short* __restrict__ W3pB,
    float* __restrict__ w0) {
  int idx = blockIdx.x*256 + threadIdx.x;
  if (idx < 1048576) {            // cbmB [4096][256], K-padded
    int row = idx >> 8, k = idx & 255;
    float v = 0.f;
    if (k < 80)       v = c [row*80 + k];
    else if (k < 144) v = bv[row*64 + (k-80)];
    else if (k < 208) v = mv[row*64 + (k-144)];
    cbmB[idx] = f2bf(v);
    return;
  }
  idx -= 1048576;
  if (idx < 262144) {             // CW [1024][256]: W_ih cols 1.. | W1 cols 256..
    int n = idx >> 8, k = idx & 255;
    float v = 0.f;
    if (n < 768) { if (k < 208) v = W_ih[n*209 + 1 + k]; }
    else         { if (k < 208) v = W1[(n-768)*464 + 256 + k]; }
    CW[idx] = f2bf(v);
    return;
  }
  idx -= 262144;
  if (idx < 196608) { WhhB[idx] = f2bf(W_hh[idx]); return; }
  idx -= 196608;
  if (idx < 65536) { int n = idx>>8, k = idx&255; W1aB[idx] = f2bf(W1[n*464+k]); return; }
  idx -= 65536;
  if (idx < 65536) { W2B[idx] = f2bf(W2[idx]); return; }
  idx -= 65536;
  if (idx < 16384) {
    int n = idx >> 8;
    float v = 0.f;
    if (n < 60) v = W3[idx];
    W3pB[idx] = f2bf(v);
    return;
  }
  idx -= 16384;
  if (idx < 768) w0[idx] = W_ih[idx*209];
}

// ---- pre-GEMM: [4096 x 1024 x 256(pad)] -> gi (+biases) / P1 (+b1) ----
__global__ __launch_bounds__(512) void k_pre(
    const unsigned short* __restrict__ A, const unsigned short* __restrict__ Bw,
    const float* __restrict__ b_ih, const float* __restrict__ b_hh,
    const float* __restrict__ b1,
    float* __restrict__ gi, float* __restrict__ P1) {
  __shared__ __align__(16) unsigned short As[128*64];
  __shared__ __align__(16) unsigned short Bs[128*64];
  int tid = threadIdx.x;
  int rb = blockIdx.x >> 3, cb = blockIdx.x & 7;
  long row0 = (long)rb * 128;
  int n0 = cb * 128;
  int wv = tid >> 6, lane = tid & 63;
  int lq = lane >> 4, l16 = lane & 15;
  int wrg = wv & 3, wcg = wv >> 2;
  f32x4 acc[2][4];
#pragma unroll
  for (int i = 0; i < 2; ++i)
#pragma unroll
    for (int j = 0; j < 4; ++j) acc[i][j] = (f32x4){0.f,0.f,0.f,0.f};
  for (int kb = 0; kb < 256; kb += 64) {
#pragma unroll
    for (int i = 0; i < 2; ++i) {
      int s = i*512 + tid;
      int r = s >> 3, cg = (s & 7) ^ (r & 7);
      *(uint4*)&As[s*8] = *(const uint4*)&A[(row0 + r)*256 + kb + cg*8];
      *(uint4*)&Bs[s*8] = *(const uint4*)&Bw[(long)(n0 + r)*256 + kb + cg*8];
    }
    __syncthreads();
#pragma unroll
    for (int kc = 0; kc < 2; ++kc) {
      int csel = kc*4 + lq;
      bf16x8 af[2];
#pragma unroll
      for (int rt = 0; rt < 2; ++rt) {
        int r = wrg*32 + rt*16 + l16;
        af[rt] = *(const bf16x8*)&As[r*64 + ((csel ^ (r & 7)))*8];
      }
#pragma unroll
      for (int ct = 0; ct < 4; ++ct) {
        int n = wcg*64 + ct*16 + l16;
        bf16x8 bfr = *(const bf16x8*)&Bs[n*64 + ((csel ^ (n & 7)))*8];
        acc[0][ct] = __builtin_amdgcn_mfma_f32_16x16x32_bf16(af[0], bfr, acc[0][ct], 0, 0, 0);
        acc[1][ct] = __builtin_amdgcn_mfma_f32_16x16x32_bf16(af[1], bfr, acc[1][ct], 0, 0, 0);
      }
    }
    __syncthreads();
  }
#pragma unroll
  for (int rt = 0; rt < 2; ++rt)
#pragma unroll
    for (int q = 0; q < 4; ++q) {
      long row = row0 + wrg*32 + rt*16 + lq*4 + q;
#pragma unroll
      for (int ct = 0; ct < 4; ++ct) {
        int n = n0 + wcg*64 + ct*16 + l16;
        float v = acc[rt][ct][q];
        if (n < 512)      gi[row*G3 + n] = v + b_ih[n] + b_hh[n];
        else if (n < 768) gi[row*G3 + n] = v + b_ih[n];
        else              P1[row*256 + (n-768)] = v + b1[n-768];
      }
    }
}

// ---- persistent GRU (best measured, ~263 us): 256 blocks x 16 rows, 512 thr.
// Whh streams from L2 each step (compiler remats the loads; all residency
// attempts R7-R13 failed). ~70% of the per-XCD L2-BW bound. ----
__global__ __attribute__((amdgpu_flat_work_group_size(512, 512)))
__attribute__((amdgpu_waves_per_eu(2, 2)))
void k_gru(
    const float* __restrict__ z, const float* __restrict__ gi,
    const unsigned short* __restrict__ WhhB, const float* __restrict__ b_hh,
    const float* __restrict__ w0, unsigned short* __restrict__ hs) {
  __shared__ __align__(16) unsigned short hbf[2*16*256];  // two 8 KB buffers
  __shared__ __align__(16) float gis[768*20];             // gi^T, stride 20 fp32
  __shared__ __align__(16) float zs[64*16];               // z^T [t][row]
  __shared__ float wls[768 + 256];                        // w0 | b_hh n-gate
  int tid = threadIdx.x;
  int wv = tid >> 6, lane = tid & 63;
  int lq = lane >> 4, l16 = lane & 15;
  int row0 = blockIdx.x * 16;
  bf16x8 wf[6][8];
#pragma unroll
  for (int g = 0; g < 3; ++g)
#pragma unroll
    for (int tt = 0; tt < 2; ++tt)
#pragma unroll
      for (int ks = 0; ks < 8; ++ks)
        wf[g*2+tt][ks] = *(const bf16x8*)&WhhB[(long)(g*256 + wv*32 + tt*16 + l16)*256 + ks*32 + lq*8];
  for (int i = tid; i < 768; i += 512) wls[i] = w0[i];
  for (int i = tid; i < 256; i += 512) wls[768 + i] = b_hh[512 + i];
  for (int i = tid; i < 1024; i += 512) {
    int t = i >> 4, r = i & 15;
    zs[i] = z[(row0+r)*64 + t];
  }
#pragma unroll
  for (int i = 0; i < 24; ++i) {
    int s = i*512 + tid;
    int r = s / 768, cc = s - r*768;
    gis[cc*20 + r] = gi[(long)(row0+r)*768 + cc];
  }
  for (int i = tid; i < 2048; i += 512) ((unsigned int*)hbf)[i] = 0u;
  float hp[2][4] = {{0.f,0.f,0.f,0.f},{0.f,0.f,0.f,0.f}};
  const int s7 = l16 & 7;
  const int arow = l16*256;
  const int r4 = lq*4;
  const int hc0 = wv*32 + l16;
  const int cr = tid >> 5, ccc = tid & 31;
  const int csrc = cr*256 + ((ccc ^ (cr & 7)))*8;
  unsigned short* cbase = hs + (long)(row0+cr)*64*256 + ccc*8;
  __syncthreads();
#pragma unroll 1
  for (int t = 0; t < 64; ++t) {
    const int co = (t & 1) << 12;
    const int no = co ^ 4096;
    float zp[4];
    {
      float4 zv4 = *(const float4*)&zs[(t ? (t-1) : 0)*16 + r4];
#pragma unroll
      for (int q = 0; q < 4; ++q) zp[q] = t ? (&zv4.x)[q] : -1.0f;
    }
    f32x4 a[6];
#pragma unroll
    for (int tt = 0; tt < 2; ++tt) {
      int hc = hc0 + tt*16;
      f32x4 gR = *(const f32x4*)&gis[hc*20 + r4];
      f32x4 gU = *(const f32x4*)&gis[(256+hc)*20 + r4];
      float w0r = wls[hc], w0u = wls[256+hc], bn = wls[768 + hc];
#pragma unroll
      for (int q = 0; q < 4; ++q) {
        a[tt][q]   = gR[q] + zp[q]*w0r;
        a[2+tt][q] = gU[q] + zp[q]*w0u;
        a[4+tt][q] = bn;
      }
    }
#pragma unroll
    for (int ks = 0; ks < 8; ++ks) {
      bf16x8 af = *(const bf16x8*)&hbf[co + arow + (((ks*4+lq) ^ s7))*8];
#pragma unroll
      for (int f = 0; f < 6; ++f)
        a[f] = __builtin_amdgcn_mfma_f32_16x16x32_bf16(af, wf[f][ks], a[f], 0, 0, 0);
    }
    if (t) {
      uint4 cdat = *(const uint4*)&hbf[co + csrc];
      *(uint4*)(cbase + (t-1)*256) = cdat;
    }
#pragma unroll
    for (int tt = 0; tt < 2; ++tt) {
      int hc = hc0 + tt*16;
      int hchunk = hc >> 3, hlow = hc & 7;
      float w0n = wls[512 + hc];
      f32x4 gN = *(const f32x4*)&gis[(512+hc)*20 + r4];
#pragma unroll
      for (int q = 0; q < 4; ++q) {
        int r = r4 + q;
        float rr = sigm(a[tt][q]);
        float uu = sigm(a[2+tt][q]);
        float nn = tanh_fast(gN[q] + zp[q]*w0n + rr*a[4+tt][q]);
        float hn = uu*(hp[tt][q] - nn) + nn;
        hp[tt][q] = hn;
        hbf[no + r*256 + ((hchunk ^ (r & 7)))*8 + hlow] = f2bf(hn);
      }
    }
    __syncthreads();
  }
  uint4 cdat = *(const uint4*)&hbf[0 + csrc];
  *(uint4*)(cbase + 63*256) = cdat;
}

// ---- MLP layer 1, in-place: Out = tanh(A @ W1a^T + P1[row>>6]) ----
__global__ __launch_bounds__(512) void k_l1(
    const unsigned short* __restrict__ A, const unsigned short* __restrict__ Bw,
    const float* __restrict__ P1, unsigned short* __restrict__ Out) {
  __shared__ __align__(16) unsigned short As[128*64];
  __shared__ __align__(16) unsigned short Bs[256*64];
  int tid = threadIdx.x;
  long row0 = (long)blockIdx.x * 128;
  int wv = tid >> 6, lane = tid & 63;
  int lq = lane >> 4, l16 = lane & 15;
  int wrg = wv & 3, wcg = wv >> 2;
  f32x4 acc[2][8];
#pragma unroll
  for (int i = 0; i < 2; ++i)
#pragma unroll
    for (int j = 0; j < 8; ++j) acc[i][j] = (f32x4){0.f,0.f,0.f,0.f};
  for (int kb = 0; kb < 256; kb += 64) {
#pragma unroll
    for (int i = 0; i < 2; ++i) {
      int s = i*512 + tid;
      int r = s >> 3, cg = (s & 7) ^ (r & 7);
      *(uint4*)&As[s*8] = *(const uint4*)&A[(row0 + r)*256 + kb + cg*8];
    }
#pragma unroll
    for (int i = 0; i < 4; ++i) {
      int s = i*512 + tid;
      int r = s >> 3, cg = (s & 7) ^ (r & 7);
      *(uint4*)&Bs[s*8] = *(const uint4*)&Bw[(long)r*256 + kb + cg*8];
    }
    __syncthreads();
#pragma unroll
    for (int kc = 0; kc < 2; ++kc) {
      int csel = kc*4 + lq;
      bf16x8 af[2];
#pragma unroll
      for (int rt = 0; rt < 2; ++rt) {
        int r = wrg*32 + rt*16 + l16;
        af[rt] = *(const bf16x8*)&As[r*64 + ((csel ^ (r & 7)))*8];
      }
#pragma unroll
      for (int ct = 0; ct < 8; ++ct) {
        int n = wcg*128 + ct*16 + l16;
        bf16x8 bfr = *(const bf16x8*)&Bs[n*64 + ((csel ^ (n & 7)))*8];
        acc[0][ct] = __builtin_amdgcn_mfma_f32_16x16x32_bf16(af[0], bfr, acc[0][ct], 0, 0, 0);
        acc[1][ct] = __builtin_amdgcn_mfma_f32_16x16x32_bf16(af[1], bfr, acc[1][ct], 0, 0, 0);
      }
    }
    __syncthreads();
  }
#pragma unroll
  for (int rt = 0; rt < 2; ++rt)
#pragma unroll
    for (int q = 0; q < 4; ++q) {
      long row = row0 + wrg*32 + rt*16 + lq*4 + q;
#pragma unroll
      for (int ct = 0; ct < 8; ++ct) {
        int n = wcg*128 + ct*16 + l16;
        float b = P1[(row >> 6)*256 + n];
        Out[row*256 + n] = f2bf(tanh_fast(acc[rt][ct][q] + b));
      }
    }
}

// ---- fused MLP layer2 + layer3 + mixture likelihood (R10/R15 proven) ----
__global__ __launch_bounds__(512) void k_l23(
    const unsigned short* __restrict__ A, const unsigned short* __restrict__ W2B,
    const float* __restrict__ b2, const unsigned short* __restrict__ W3pB,
    const float* __restrict__ b3, const float* __restrict__ z,
    float* __restrict__ ll) {
  __shared__ __align__(16) unsigned short As[128*64];
  __shared__ __align__(16) unsigned short Bs[256*64];
  __shared__ __align__(16) unsigned short h2s[128*256];
  int tid = threadIdx.x;
  long row0 = (long)blockIdx.x * 128;
  int wv = tid >> 6, lane = tid & 63;
  int lq = lane >> 4, l16 = lane & 15;
  int wrg = wv & 3, wcg = wv >> 2;
  f32x4 acc[2][8];
#pragma unroll
  for (int i = 0; i < 2; ++i)
#pragma unroll
    for (int j = 0; j < 8; ++j) acc[i][j] = (f32x4){0.f,0.f,0.f,0.f};
  for (int kb = 0; kb < 256; kb += 64) {
#pragma unroll
    for (int i = 0; i < 2; ++i) {
      int s = i*512 + tid;
      int r = s >> 3, cg = (s & 7) ^ (r & 7);
      *(uint4*)&As[s*8] = *(const uint4*)&A[(row0 + r)*256 + kb + cg*8];
    }
#pragma unroll
    for (int i = 0; i < 4; ++i) {
      int s = i*512 + tid;
      int r = s >> 3, cg = (s & 7) ^ (r & 7);
      *(uint4*)&Bs[s*8] = *(const uint4*)&W2B[(long)r*256 + kb + cg*8];
    }
    __syncthreads();
#pragma unroll
    for (int kc = 0; kc < 2; ++kc) {
      int csel = kc*4 + lq;
      bf16x8 af[2];
#pragma unroll
      for (int rt = 0; rt < 2; ++rt) {
        int r = wrg*32 + rt*16 + l16;
        af[rt] = *(const bf16x8*)&As[r*64 + ((csel ^ (r & 7)))*8];
      }
#pragma unroll
      for (int ct = 0; ct < 8; ++ct) {
        int n = wcg*128 + ct*16 + l16;
        bf16x8 bfr = *(const bf16x8*)&Bs[n*64 + ((csel ^ (n & 7)))*8];
        acc[0][ct] = __builtin_amdgcn_mfma_f32_16x16x32_bf16(af[0], bfr, acc[0][ct], 0, 0, 0);
        acc[1][ct] = __builtin_amdgcn_mfma_f32_16x16x32_bf16(af[1], bfr, acc[1][ct], 0, 0, 0);
      }
    }
    __syncthreads();
  }
  // h2 -> LDS (bf16, swizzled for A-side reads)
#pragma unroll
  for (int rt = 0; rt < 2; ++rt)
#pragma unroll
    for (int q = 0; q < 4; ++q) {
      int lr = wrg*32 + rt*16 + lq*4 + q;
#pragma unroll
      for (int ct = 0; ct < 8; ++ct) {
        int n = wcg*128 + ct*16 + l16;
        h2s[lr*256 + (((n >> 3) ^ swz(lr))*8 + (n & 7))] =
            f2bf(tanh_fast(acc[rt][ct][q] + b2[n]));
      }
    }
  // stage W3p into Bs (64 x 256), swizzled
#pragma unroll
  for (int i = 0; i < 4; ++i) {
    int s = i*512 + tid;
    int r = s >> 5, cc = s & 31;
    *(uint4*)&Bs[r*256 + ((cc ^ swz(r)))*8] = *(const uint4*)&W3pB[r*256 + cc*8];
  }
  __syncthreads();
  // stage 2: each wave computes its own 16 rows x 64 params
  f32x4 pacc[4];
#pragma unroll
  for (int j = 0; j < 4; ++j) pacc[j] = (f32x4){0.f,0.f,0.f,0.f};
#pragma unroll
  for (int ks = 0; ks < 8; ++ks) {
    int chunk = ks*4 + lq;
    int ar = wv*16 + l16;
    bf16x8 af = *(const bf16x8*)&h2s[ar*256 + ((chunk ^ swz(ar)))*8];
#pragma unroll
    for (int ct = 0; ct < 4; ++ct) {
      int br = ct*16 + l16;
      bf16x8 bfr = *(const bf16x8*)&Bs[br*256 + ((chunk ^ swz(br)))*8];
      pacc[ct] = __builtin_amdgcn_mfma_f32_16x16x32_bf16(af, bfr, pacc[ct], 0, 0, 0);
    }
  }
  // params to own LDS region (reuse h2s rows of this wave), stride 68 fp32
  float* Ps = (float*)&h2s[wv*16*256];
#pragma unroll
  for (int ct = 0; ct < 4; ++ct) {
    int n = ct*16 + l16;
    float b = (n < 60) ? b3[n] : 0.0f;
#pragma unroll
    for (int q = 0; q < 4; ++q)
      Ps[(lq*4 + q)*68 + n] = pacc[ct][q] + b;
  }
  // per-row likelihood (wave-internal)
  if (lane < 16) {
    long grow = row0 + wv*16 + lane;
    float zv = z[grow];
    const float* p = &Ps[lane*68];
    float mx1 = -1e30f;
#pragma unroll
    for (int i = 0; i < NK; ++i) mx1 = fmaxf(mx1, p[i]);
    float s1 = 0.0f;
#pragma unroll
    for (int i = 0; i < NK; ++i) s1 += __expf(p[i] - mx1);
    float lse1 = mx1 + __logf(s1);
    float a[NK];
    float mx2 = -1e30f;
#pragma unroll
    for (int i = 0; i < NK; ++i) {
      float lg = p[i], me = p[20+i], ls = p[40+i];
      float e = __expf(-ls);
      float d = (zv - me) * e;
      float ai = -0.5f*d*d - ls - 0.5f*LOG2PI + lg;
      a[i] = ai;
      mx2 = fmaxf(mx2, ai);
    }
    float s2 = 0.0f;
#pragma unroll
    for (int i = 0; i < NK; ++i) s2 += __expf(a[i] - mx2);
    float lse2 = mx2 + __logf(s2);
    ll[grow] = lse2 - lse1;
  }
}

// out[b] = sum_{t < S_b} ll[b,t]
__global__ __launch_bounds__(256) void k_final(const float* __restrict__ bv,
    const float* __restrict__ mv, const float* __restrict__ ll,
    float* __restrict__ out) {
  int tid = threadIdx.x;
  int wave = tid >> 6, lane = tid & 63;
  int b = blockIdx.x*4 + wave;
  float q = mv[b*64 + lane] * (1.0f - bv[b*64 + lane]);
  unsigned long long bal = __ballot(q > 0.5f);
  int S = __popcll(bal);
  float val = (lane < S) ? ll[(long)b*64 + lane] : 0.0f;
#pragma unroll
  for (int off = 32; off > 0; off >>= 1) val += __shfl_down(val, off);
  if (lane == 0) out[b] = val;
}

extern "C" void kernel_launch(void* const* d_in, const int* in_sizes, int n_in,
                              void* d_out, int out_size, void* d_ws, size_t ws_size,
                              hipStream_t stream) {
  const float* z    = (const float*)d_in[0];
  const float* c    = (const float*)d_in[1];
  const float* bv   = (const float*)d_in[2];
  const float* mv   = (const float*)d_in[3];
  const float* W_ih = (const float*)d_in[4];
  const float* W_hh = (const float*)d_in[5];
  const float* b_ih = (const float*)d_in[6];
  const float* b_hh = (const float*)d_in[7];
  const float* W1   = (const float*)d_in[8];
  const float* b1   = (const float*)d_in[9];
  const float* W2   = (const float*)d_in[10];
  const float* b2   = (const float*)d_in[11];
  const float* W3   = (const float*)d_in[12];
  const float* b3   = (const float*)d_in[13];
  float* out = (float*)d_out;

  char* p = (char*)d_ws;
  auto alloc = [&](size_t bytes) {
    char* q = p;
    p += (bytes + 255) & ~(size_t)255;
    return q;
  };
  unsigned short* cbmB = (unsigned short*)alloc((size_t)BATCH*256*2);
  unsigned short* CW   = (unsigned short*)alloc((size_t)1024*256*2);
  unsigned short* WhhB = (unsigned short*)alloc((size_t)G3*256*2);
  unsigned short* W1aB = (unsigned short*)alloc((size_t)256*256*2);
  unsigned short* W2B  = (unsigned short*)alloc((size_t)256*256*2);
  unsigned short* W3pB = (unsigned short*)alloc((size_t)64*256*2);
  float* w0 = (float*)alloc((size_t)G3*4);
  float* gi = (float*)alloc((size_t)BATCH*G3*4);
  float* P1 = (float*)alloc((size_t)BATCH*256*4);
  float* ll = (float*)alloc((size_t)NROW*4);
  unsigned short* hs = (unsigned short*)alloc((size_t)NROW*HDIM*2);

  k_cvtall<<<6468, 256, 0, stream>>>(c, bv, mv, W_ih, W_hh, W1, W2, W3,
                                     cbmB, CW, WhhB, W1aB, W2B, W3pB, w0);
  k_pre<<<256, 512, 0, stream>>>(cbmB, CW, b_ih, b_hh, b1, gi, P1);
  k_gru<<<256, 512, 0, stream>>>(z, gi, WhhB, b_hh, w0, hs);
  k_l1<<<NROW/128, 512, 0, stream>>>(hs, W1aB, P1, hs);
  k_l23<<<NROW/128, 512, 0, stream>>>(hs, W2B, b2, W3pB, b3, z, ll);
  k_final<<<BATCH/4, 256, 0, stream>>>(bv, mv, ll, out);
}